// Round 1
// baseline (165.618 us; speedup 1.0000x reference)
//
#include <hip/hip_runtime.h>
#include <math.h>

// Problem constants (from reference): B=128, IN=256, H=1024, L=256
// LA=LB=128 (scan does 128 steps of layerA-then-layerB), nA=512, nB=511.
#define NBATCH 128
#define NIN    256
#define NH     1024
#define NSTEPS 128
#define NA     512
#define NB     511
#define NBP    512   // padded pair stride for B table

// Workspace layout (in floats):
//  tabA : [128][512] float4 {c0,s0,c1,s1}   = 262144 floats (1 MB)
//  tabB : [128][512] float4 (pair 511 pad)  = 262144 floats (1 MB)
//  ihR  : [128][1024]                       = 131072 floats (512 KB)
//  ihI  : [128][1024]                       = 131072 floats (512 KB)
#define TABA_OFF 0
#define TABB_OFF (NSTEPS * NBP * 4)
#define IHR_OFF  (TABB_OFF + NSTEPS * NBP * 4)
#define IHI_OFF  (IHR_OFF + NBATCH * NH)

// ---------------------------------------------------------------------------
// Kernel 1: precompute cos/sin tables for all mesh angles.
// ---------------------------------------------------------------------------
__global__ __launch_bounds__(256) void trig_kernel(
    const float* __restrict__ A0, const float* __restrict__ A1,
    const float* __restrict__ B0, const float* __restrict__ B1,
    float* __restrict__ ws)
{
    int idx = blockIdx.x * blockDim.x + threadIdx.x;
    const int totalA = NSTEPS * NA;          // 65536
    const int totalB = NSTEPS * NB;          // 65408
    if (idx < totalA) {
        int l = idx >> 9;        // /512
        int p = idx & 511;
        float a0 = A0[idx], a1 = A1[idx];
        float4 v = make_float4(cosf(a0), sinf(a0), cosf(a1), sinf(a1));
        ((float4*)(ws + TABA_OFF))[l * NBP + p] = v;
    } else {
        int j = idx - totalA;
        if (j < totalB) {
            int l = j / NB;
            int p = j - l * NB;
            float b0 = B0[j], b1 = B1[j];
            float4 v = make_float4(cosf(b0), sinf(b0), cosf(b1), sinf(b1));
            ((float4*)(ws + TABB_OFF))[l * NBP + p] = v;
        }
    }
}

// ---------------------------------------------------------------------------
// Kernel 2: complex CLinear  ih = inputs @ W^T + bias  (fp32 vector ALU).
// Block = 256 threads covering 16 h x 16 b. Inputs staged in LDS (padded).
// ---------------------------------------------------------------------------
__global__ __launch_bounds__(256) void gemm_kernel(
    const float* __restrict__ inR, const float* __restrict__ inI,
    const float* __restrict__ wR,  const float* __restrict__ wI,
    const float* __restrict__ biasR, const float* __restrict__ biasI,
    float* __restrict__ ws)
{
    __shared__ float ldsR[16 * 260];
    __shared__ float ldsI[16 * 260];
    const int h0 = blockIdx.x * 16;
    const int b0 = blockIdx.y * 16;
    const int tid = threadIdx.x;

    // Stage 16 input rows (R and I), coalesced float4 loads.
    for (int e = tid; e < 16 * 64; e += 256) {
        int bb = e >> 6;      // 0..15
        int k4 = e & 63;      // 0..63
        float4 vr = ((const float4*)(inR + (b0 + bb) * NIN))[k4];
        float4 vi = ((const float4*)(inI + (b0 + bb) * NIN))[k4];
        *(float4*)&ldsR[bb * 260 + k4 * 4] = vr;
        *(float4*)&ldsI[bb * 260 + k4 * 4] = vi;
    }
    __syncthreads();

    const int hl = tid & 15, bl = tid >> 4;
    const int h = h0 + hl, bb = b0 + bl;
    const float4* wr4 = (const float4*)(wR + h * NIN);
    const float4* wi4 = (const float4*)(wI + h * NIN);

    float accR = 0.f, accI = 0.f;
#pragma unroll 8
    for (int k4 = 0; k4 < 64; ++k4) {
        float4 wr = wr4[k4];
        float4 wi = wi4[k4];
        float4 xr = *(const float4*)&ldsR[bl * 260 + k4 * 4];
        float4 xi = *(const float4*)&ldsI[bl * 260 + k4 * 4];
        accR += xr.x * wr.x - xi.x * wi.x;
        accI += xr.x * wi.x + xi.x * wr.x;
        accR += xr.y * wr.y - xi.y * wi.y;
        accI += xr.y * wi.y + xi.y * wr.y;
        accR += xr.z * wr.z - xi.z * wi.z;
        accI += xr.z * wi.z + xi.z * wr.z;
        accR += xr.w * wr.w - xi.w * wi.w;
        accI += xr.w * wi.w + xi.w * wr.w;
    }
    float* ihR = ws + IHR_OFF;
    float* ihI = ws + IHI_OFF;
    ihR[bb * NH + h] = accR + biasR[h];
    ihI[bb * NH + h] = accI + biasI[h];
}

// ---------------------------------------------------------------------------
// Kernel 3: Clements mesh (128 x (A,B) layers) + phase + add + modReLU.
// One block per batch row; thread t owns channels 4t..4t+3 in registers.
// A-layer: fully register-local. B-layer: one LDS boundary exchange,
// double-buffered -> exactly one __syncthreads per step.
// ---------------------------------------------------------------------------
__global__ __launch_bounds__(256) void mesh_kernel(
    const float* __restrict__ stateR, const float* __restrict__ stateI,
    const float* __restrict__ omega,  const float* __restrict__ mod_bias,
    const float* __restrict__ ws, float* __restrict__ out)
{
    // [buf][which: 0=ch0, 1=ch3][thread][r/i]
    __shared__ float xch[2][2][256][2];

    const int b = blockIdx.x;
    const int t = threadIdx.x;
    const float4* tA = (const float4*)(ws + TABA_OFF);
    const float4* tB = (const float4*)(ws + TABB_OFF);

    float4 sr = ((const float4*)(stateR + b * NH))[t];
    float4 si = ((const float4*)(stateI + b * NH))[t];
    float cr0 = sr.x, cr1 = sr.y, cr2 = sr.z, cr3 = sr.w;
    float ci0 = si.x, ci1 = si.y, ci2 = si.z, ci3 = si.w;

    // Prefetch layer-0 angle tables. Negative index for t==0 (b_l) lands in
    // the tail of tabA — in-bounds of ws, and the value is never used.
    float4 a0  = tA[2 * t];
    float4 a1  = tA[2 * t + 1];
    float4 b_l = tB[2 * t - 1];
    float4 b_c = tB[2 * t];
    float4 b_r = tB[2 * t + 1];   // t==255: padded slot, never used

    for (int l = 0; l < NSTEPS; ++l) {
        // --- software prefetch next layer's angles (hidden across barrier)
        const int ln = (l < NSTEPS - 1) ? (l + 1) : (NSTEPS - 1);
        float4 na0 = tA[ln * NBP + 2 * t];
        float4 na1 = tA[ln * NBP + 2 * t + 1];
        float4 nbl = tB[ln * NBP + 2 * t - 1];
        float4 nbc = tB[ln * NBP + 2 * t];
        float4 nbr = tB[ln * NBP + 2 * t + 1];

        // --- layer A: pairs (ch0,ch1) and (ch2,ch3), register-local
        {
            float pr = a0.x * cr0 - a0.y * ci0;
            float pi = a0.y * cr0 + a0.x * ci0;
            float tr = cr1, ti = ci1;
            cr0 = a0.z * pr - a0.w * ti;
            ci0 = a0.z * pi + a0.w * tr;
            cr1 = a0.z * tr - a0.w * pi;
            ci1 = a0.z * ti + a0.w * pr;
        }
        {
            float pr = a1.x * cr2 - a1.y * ci2;
            float pi = a1.y * cr2 + a1.x * ci2;
            float tr = cr3, ti = ci3;
            cr2 = a1.z * pr - a1.w * ti;
            ci2 = a1.z * pi + a1.w * tr;
            cr3 = a1.z * tr - a1.w * pi;
            ci3 = a1.z * ti + a1.w * pr;
        }

        // --- publish post-A boundary channels
        const int buf = l & 1;
        xch[buf][0][t][0] = cr0; xch[buf][0][t][1] = ci0;
        xch[buf][1][t][0] = cr3; xch[buf][1][t][1] = ci3;
        __syncthreads();

        // --- layer B local pair (ch1, ch2), pair index 2t
        {
            float pr = b_c.x * cr1 - b_c.y * ci1;
            float pi = b_c.y * cr1 + b_c.x * ci1;
            float tr = cr2, ti = ci2;
            cr1 = b_c.z * pr - b_c.w * ti;
            ci1 = b_c.z * pi + b_c.w * tr;
            cr2 = b_c.z * tr - b_c.w * pi;
            ci2 = b_c.z * ti + b_c.w * pr;
        }
        // --- boundary pair (ch3 with right neighbor's ch0), pair 2t+1.
        if (t < 255) {
            float rr = xch[buf][0][t + 1][0];
            float ri = xch[buf][0][t + 1][1];
            float pr = b_r.x * cr3 - b_r.y * ci3;
            float pi = b_r.y * cr3 + b_r.x * ci3;
            cr3 = b_r.z * pr - b_r.w * ri;
            ci3 = b_r.z * pi + b_r.w * rr;
        }
        // --- b-side of left boundary pair (left's ch3 with own ch0), pair 2t-1
        if (t > 0) {
            float lr = xch[buf][1][t - 1][0];
            float li = xch[buf][1][t - 1][1];
            float pr = b_l.x * lr - b_l.y * li;
            float pi = b_l.y * lr + b_l.x * li;
            float nr = b_l.z * cr0 - b_l.w * pi;
            float ni = b_l.z * ci0 + b_l.w * pr;
            cr0 = nr; ci0 = ni;
        }

        a0 = na0; a1 = na1; b_l = nbl; b_c = nbc; b_r = nbr;
    }

    // --- epilogue: diagonal phase, add ih, modReLU, store (2,B,H)
    float4 om = ((const float4*)omega)[t];
    float4 mb = ((const float4*)mod_bias)[t];
    float4 ir = ((const float4*)(ws + IHR_OFF + b * NH))[t];
    float4 ii = ((const float4*)(ws + IHI_OFF + b * NH))[t];

    float hr[4] = {cr0, cr1, cr2, cr3};
    float hi[4] = {ci0, ci1, ci2, ci3};
    float oms[4] = {om.x, om.y, om.z, om.w};
    float mbs[4] = {mb.x, mb.y, mb.z, mb.w};
    float irs[4] = {ir.x, ir.y, ir.z, ir.w};
    float iis[4] = {ii.x, ii.y, ii.z, ii.w};
    float orr[4], ori[4];
#pragma unroll
    for (int j = 0; j < 4; ++j) {
        float co = cosf(oms[j]);
        float so = sinf(oms[j]);
        float hhR = co * hr[j] - so * hi[j];
        float hhI = so * hr[j] + co * hi[j];
        float zr = irs[j] + hhR;
        float zi = iis[j] + hhI;
        float mag = sqrtf(zr * zr + zi * zi);
        float sc = fmaxf(mag + mbs[j], 0.f) / fmaxf(mag, 1e-8f);
        orr[j] = sc * zr;
        ori[j] = sc * zi;
    }
    float4 o0 = make_float4(orr[0], orr[1], orr[2], orr[3]);
    float4 o1 = make_float4(ori[0], ori[1], ori[2], ori[3]);
    ((float4*)(out + b * NH))[t] = o0;
    ((float4*)(out + NBATCH * NH + b * NH))[t] = o1;
}

// ---------------------------------------------------------------------------
extern "C" void kernel_launch(void* const* d_in, const int* in_sizes, int n_in,
                              void* d_out, int out_size, void* d_ws, size_t ws_size,
                              hipStream_t stream)
{
    const float* inputsR = (const float*)d_in[0];
    const float* inputsI = (const float*)d_in[1];
    const float* stateR  = (const float*)d_in[2];
    const float* stateI  = (const float*)d_in[3];
    const float* weightR = (const float*)d_in[4];
    const float* weightI = (const float*)d_in[5];
    const float* biasR   = (const float*)d_in[6];
    const float* biasI   = (const float*)d_in[7];
    const float* angleA0 = (const float*)d_in[8];
    const float* angleA1 = (const float*)d_in[9];
    const float* angleB0 = (const float*)d_in[10];
    const float* angleB1 = (const float*)d_in[11];
    const float* omega   = (const float*)d_in[12];
    const float* mod_b   = (const float*)d_in[13];
    float* ws = (float*)d_ws;
    float* out = (float*)d_out;

    // 1) trig tables: 65536 (A) + 65408 (B) = 130944 pair-entries
    {
        int total = NSTEPS * NA + NSTEPS * NB;           // 130944
        int blocks = (total + 255) / 256;                // 512
        hipLaunchKernelGGL(trig_kernel, dim3(blocks), dim3(256), 0, stream,
                           angleA0, angleA1, angleB0, angleB1, ws);
    }
    // 2) complex CLinear -> ws(ihR, ihI)
    hipLaunchKernelGGL(gemm_kernel, dim3(NH / 16, NBATCH / 16), dim3(256), 0,
                       stream, inputsR, inputsI, weightR, weightI,
                       biasR, biasI, ws);
    // 3) mesh + phase + add + modReLU -> out
    hipLaunchKernelGGL(mesh_kernel, dim3(NBATCH), dim3(256), 0, stream,
                       stateR, stateI, omega, mod_b, ws, out);
}